// Round 7
// baseline (221.071 us; speedup 1.0000x reference)
//
#include <hip/hip_runtime.h>

// RecursiveNN root = sum of leaf embeddings: out[b,d] = sum_l emb[ids[b,l], d]
// B=4096, L=64, D=300, VOCAB=100000, fp32.
//
// R6 = R5 resubmitted (GPU acquisition timeout, no data collected).
// R5: two-phase. The 480MB ws-poison before every timed launch evicts L3,
// so the gather's compulsory 120MB table fetch was random-1200B-granule HBM
// traffic at ~2.6 TB/s (R4 counters: FETCH 175MB, 69.7us). Phase 1 streams
// the table sequentially (fills Infinity Cache at ~6+ TB/s); phase 2 is the
// gather, now L3-hit. Same-stream launches = device-wide barrier between.

#define NB 4096
#define NL 64
#define ND 300
#define ND4 75          // float4 per row
#define VOCAB 100000
#define TBL_F4 (VOCAB * ND4)   // 7,500,000 float4

// ---- Phase 1: sequential warm of the embedding table into L3 ----
__global__ __launch_bounds__(256, 8) void warm_table(
    const float4* __restrict__ emb4, float* __restrict__ ws)
{
    const int gid = blockIdx.x * blockDim.x + threadIdx.x;
    const int stride = gridDim.x * blockDim.x;
    float s = 0.f;
    for (int i = gid; i < TBL_F4; i += stride) {
        const float4 v = emb4[i];
        s += v.x + v.y + v.z + v.w;
    }
    // keep loads live; writes (if any) are benign scratch
    if (s == 1234.56789f) ws[gid] = s;
}

// ---- Phase 2: gather+reduce (R2 structure: 2 waves/tree, 32 waves/CU) ----
__global__ __launch_bounds__(256, 8) void recnn_root_sum(
    const int* __restrict__ word_ids,     // [NB, NL]
    const float4* __restrict__ emb4,      // [VOCAB, ND4]
    float* __restrict__ out)              // [NB, ND]
{
    __shared__ float partial[4][ND];

    const int tid  = threadIdx.x;
    const int wave = tid >> 6;
    const int lane = tid & 63;

    const int tree_local = wave >> 1;          // 0..1
    const int half       = wave & 1;           // which 32 rows
    const int tree       = blockIdx.x * 2 + tree_local;

    const int myid = word_ids[tree * NL + half * 32 + (lane & 31)];

    float4 acc0 = make_float4(0.f, 0.f, 0.f, 0.f);
    #pragma unroll 8
    for (int i = 0; i < 32; ++i) {
        const int row = __builtin_amdgcn_readlane(myid, i);
        const float4 v = emb4[(size_t)row * ND4 + lane];
        acc0.x += v.x; acc0.y += v.y; acc0.z += v.z; acc0.w += v.w;
    }
    *reinterpret_cast<float4*>(&partial[wave][lane * 4]) = acc0;

    if (lane < ND4 - 64) {
        float4 acc1 = make_float4(0.f, 0.f, 0.f, 0.f);
        #pragma unroll 8
        for (int i = 0; i < 32; ++i) {
            const int row = __builtin_amdgcn_readlane(myid, i);
            const float4 v = emb4[(size_t)row * ND4 + 64 + lane];
            acc1.x += v.x; acc1.y += v.y; acc1.z += v.z; acc1.w += v.w;
        }
        *reinterpret_cast<float4*>(&partial[wave][256 + lane * 4]) = acc1;
    }
    __syncthreads();

    for (int t = tid; t < 2 * ND; t += 256) {
        const int tl = t / ND;
        const int c  = t - tl * ND;
        out[(size_t)(blockIdx.x * 2 + tl) * ND + c] =
            partial[2 * tl][c] + partial[2 * tl + 1][c];
    }
}

extern "C" void kernel_launch(void* const* d_in, const int* in_sizes, int n_in,
                              void* d_out, int out_size, void* d_ws, size_t ws_size,
                              hipStream_t stream) {
    const int*    word_ids = (const int*)d_in[0];      // [4096, 64] int32
    const float4* emb4     = (const float4*)d_in[1];   // [100000, 75] float4
    float*        out      = (float*)d_out;            // [4096, 300] f32
    float*        ws       = (float*)d_ws;

    warm_table<<<2048, 256, 0, stream>>>(emb4, ws);
    recnn_root_sum<<<NB / 2, 256, 0, stream>>>(word_ids, emb4, out);
}

// Round 8
// 192.501 us; speedup vs baseline: 1.1484x; 1.1484x over previous
//
#include <hip/hip_runtime.h>

// RecursiveNN root = sum of leaf embeddings: out[b,d] = sum_l emb[ids[b,l], d]
// B=4096, L=64, D=300, VOCAB=100000, fp32.
//
// R8: transaction-packed gather. R7 showed the table is already MALL-resident
// (harness restores it pre-launch) and the ~2.6TB/s miss-path rate is the
// scattered-request service wall. Test transaction-rate vs byte-rate limit:
// pack 2 rows (150 float4) into 3 wave-loads instead of 4 (2 full + 2 skinny):
//   load0: lanes 0..63  -> row even, col4 lane            (1024B)
//   load1: lanes 0..10  -> row even, col4 64+lane
//          lanes 11..63 -> row odd,  col4 lane-11         (1024B)
//   load2: lanes 0..21  -> row odd,  col4 53+lane         (704B)
// Per-lane accumulators accA/accB/accC have FIXED column meaning; final
// merge: col4 c<53: A[c]+B[c+11]; 53<=c<64: A[c]+C[c-53]; c>=64: B[c-64]+C[c-53].
// Structure: 2 waves/tree (32 rows each), 2048 blocks x 4 waves, no warm.

#define NB 4096
#define NL 64
#define ND 300
#define ND4 75

__global__ __launch_bounds__(256, 8) void recnn_root_sum(
    const int* __restrict__ word_ids,     // [NB, NL]
    const float4* __restrict__ emb4,      // [VOCAB, ND4]
    float* __restrict__ out)              // [NB, ND]
{
    __shared__ float sA[4][64 * 4];   // 4 KB: col4 0..63 (even rows)
    __shared__ float sB[4][64 * 4];   // 4 KB: col4 64+l (l<11, even) / l-11 (l>=11, odd)
    __shared__ float sC[4][22 * 4];   // 1.4 KB: col4 53+l (odd rows)

    const int tid  = threadIdx.x;
    const int wave = tid >> 6;
    const int lane = tid & 63;

    const int tree_local = wave >> 1;          // 0..1
    const int half       = wave & 1;           // which 32 rows
    const int tree       = blockIdx.x * 2 + tree_local;

    // lanes 0..31 hold this wave's 32 leaf ids (32..63 duplicate).
    const int myid = word_ids[tree * NL + half * 32 + (lane & 31)];

    const bool blo = lane < 11;   // load1 row select
    const bool cac = lane < 22;   // load2 active

    float4 accA = make_float4(0.f, 0.f, 0.f, 0.f);
    float4 accB = make_float4(0.f, 0.f, 0.f, 0.f);
    float4 accC = make_float4(0.f, 0.f, 0.f, 0.f);

    #pragma unroll 1
    for (int k = 0; k < 16; k += 2) {       // 2 row-pairs per batch -> 6 loads
        float4 v[6];
        #pragma unroll
        for (int p = 0; p < 2; ++p) {
            const int r0 = __builtin_amdgcn_readlane(myid, 2 * (k + p));
            const int r1 = __builtin_amdgcn_readlane(myid, 2 * (k + p) + 1);
            const size_t b0 = (size_t)r0 * ND4;
            const size_t b1 = (size_t)r1 * ND4;
            v[3 * p + 0] = emb4[b0 + lane];
            v[3 * p + 1] = emb4[blo ? (b0 + 64 + lane) : (b1 + lane - 11)];
            v[3 * p + 2] = cac ? emb4[b1 + 53 + lane]
                               : make_float4(0.f, 0.f, 0.f, 0.f);
        }
        #pragma unroll
        for (int p = 0; p < 2; ++p) {
            accA.x += v[3*p+0].x; accA.y += v[3*p+0].y;
            accA.z += v[3*p+0].z; accA.w += v[3*p+0].w;
            accB.x += v[3*p+1].x; accB.y += v[3*p+1].y;
            accB.z += v[3*p+1].z; accB.w += v[3*p+1].w;
            accC.x += v[3*p+2].x; accC.y += v[3*p+2].y;
            accC.z += v[3*p+2].z; accC.w += v[3*p+2].w;
        }
    }

    *reinterpret_cast<float4*>(&sA[wave][lane * 4]) = accA;
    *reinterpret_cast<float4*>(&sB[wave][lane * 4]) = accB;
    if (cac)
        *reinterpret_cast<float4*>(&sC[wave][lane * 4]) = accC;
    __syncthreads();

    // Final merge: 2 trees x 300 cols; each col4 has exactly 2 contributors
    // per wave; sum the tree's 2 waves.
    for (int x = tid; x < 2 * ND; x += 256) {
        const int tl = x / ND;
        const int c  = x - tl * ND;         // 0..299
        const int c4 = c >> 2, j = c & 3;
        float s = 0.f;
        #pragma unroll
        for (int wv = 0; wv < 2; ++wv) {
            const int w = 2 * tl + wv;
            float p;
            if (c4 < 53)       p = sA[w][c4 * 4 + j] + sB[w][(c4 + 11) * 4 + j];
            else if (c4 < 64)  p = sA[w][c4 * 4 + j] + sC[w][(c4 - 53) * 4 + j];
            else               p = sB[w][(c4 - 64) * 4 + j] + sC[w][(c4 - 53) * 4 + j];
            s += p;
        }
        out[(size_t)(blockIdx.x * 2 + tl) * ND + c] = s;
    }
}

extern "C" void kernel_launch(void* const* d_in, const int* in_sizes, int n_in,
                              void* d_out, int out_size, void* d_ws, size_t ws_size,
                              hipStream_t stream) {
    const int*    word_ids = (const int*)d_in[0];      // [4096, 64] int32
    const float4* emb4     = (const float4*)d_in[1];   // [100000, 75] float4
    float*        out      = (float*)d_out;            // [4096, 300] f32

    recnn_root_sum<<<NB / 2, 256, 0, stream>>>(word_ids, emb4, out);
}